// Round 1
// baseline (192.954 us; speedup 1.0000x reference)
//
#include <hip/hip_runtime.h>
#include <math.h>

#define BB 64
#define LL 1024
#define HH 256
#define TT 128
#define D_ID 128
#define D_SZ 64
#define D_POS 128
#define DX 192   // D_ID + D_SZ

typedef short s16x8 __attribute__((ext_vector_type(8)));
typedef float f32x16 __attribute__((ext_vector_type(16)));
typedef unsigned short u16x8 __attribute__((ext_vector_type(8)));
typedef unsigned short u16x4 __attribute__((ext_vector_type(4)));

__device__ __forceinline__ unsigned short f2bf(float f) {
    unsigned u = __float_as_uint(f);
    unsigned r = u + 0x7fffu + ((u >> 16) & 1u);   // RNE
    return (unsigned short)(r >> 16);
}

__device__ __forceinline__ s16x8 pack8(float4 a, float4 b) {
    u16x8 p;
    p[0] = f2bf(a.x); p[1] = f2bf(a.y); p[2] = f2bf(a.z); p[3] = f2bf(a.w);
    p[4] = f2bf(b.x); p[5] = f2bf(b.y); p[6] = f2bf(b.z); p[7] = f2bf(b.w);
    return (s16x8)p;
}

// =====================================================================
// K1: fused embed + gates + sv/rv(t<127)
//   blocks [0,256): gates for output column j = blockIdx.x.
//     xh = concat(emb_id, emb_sz, h0) staged in LDS transposed (k-major),
//     in TWO 224-wide half-stages so LDS stays at 57.6 KB (2 blocks/CU).
//     Summation order identical to the previous xh_t-based version.
//   blocks [256,320): sv/rv dot products for t<127 (h_new-independent;
//     t=127 is computed inside attn_kernel which owns h_new by then).
// =====================================================================
__global__ void gates_kernel(const int* __restrict__ obj_id,
                             const int* __restrict__ obj_size,
                             const float* __restrict__ h0,
                             const float* __restrict__ c0,
                             const float* __restrict__ obj_id_table,
                             const float* __restrict__ obj_size_table,
                             const float* __restrict__ history,
                             const float* __restrict__ pos_table,
                             const float* __restrict__ W_ih,
                             const float* __restrict__ W_hh,
                             const float* __restrict__ b_ih,
                             const float* __restrict__ b_hh,
                             const float* __restrict__ scorer_W,
                             const float* __restrict__ reuse_W,
                             float* __restrict__ h_new,
                             float* __restrict__ sv,
                             float* __restrict__ rv) {
    int tid = threadIdx.x;

    if (blockIdx.x >= HH) {
        // ---- sv/rv part: b = blk-256, thread -> (which = tid>>7, t = tid&127)
        int b = blockIdx.x - HH;
        int which = tid >> 7;
        int t = tid & 127;
        if (t == TT - 1) return;        // t=127 handled in attn_kernel
        const float* w = which ? reuse_W : scorer_W;
        const float* hrow = history + ((size_t)b * (TT - 1) + t) * HH;
        float acc = 0.f;
#pragma unroll 8
        for (int k = 0; k < HH / 4; ++k) {
            float4 hv = *(const float4*)(hrow + 4 * k);
            float4 wv = *(const float4*)(w + 4 * k);
            acc += hv.x * wv.x + hv.y * wv.y + hv.z * wv.z + hv.w * wv.w;
        }
        const float* prow = pos_table + (size_t)t * D_POS;
#pragma unroll 8
        for (int k = 0; k < D_POS / 4; ++k) {
            float4 pv = *(const float4*)(prow + 4 * k);
            float4 wv = *(const float4*)(w + HH + 4 * k);
            acc += pv.x * wv.x + pv.y * wv.y + pv.z * wv.z + pv.w * wv.w;
        }
        (which ? rv : sv)[b * TT + t] = acc;
        return;
    }

    // ---- gates part
    __shared__ float xhS[224 * 64];   // 56 KB, half of xh at a time, k-major
    __shared__ float gS[256];

    int j = blockIdx.x;
    int b = tid & 63;
    int q = __builtin_amdgcn_readfirstlane(tid >> 6);
    int r = q * HH + j;
    const float* wi = W_ih + (size_t)r * DX;
    const float* wh = W_hh + (size_t)r * HH;
    float acc = b_ih[r] + b_hh[r];

    int sb = tid >> 2;      // staging: 4 threads per batch row
    int c4 = tid & 3;

    // ---- half-stage 1: k in [0,224) = emb_id(128) + emb_sz(64) + h0[0:32)
    {
        const float* row = obj_id_table + (size_t)obj_id[sb] * D_ID;
#pragma unroll
        for (int i = 0; i < 8; ++i) {
            int k = c4 * 4 + i * 16;
            float4 v = *(const float4*)(row + k);
            xhS[(k + 0) * 64 + sb] = v.x;
            xhS[(k + 1) * 64 + sb] = v.y;
            xhS[(k + 2) * 64 + sb] = v.z;
            xhS[(k + 3) * 64 + sb] = v.w;
        }
        const float* srow = obj_size_table + (size_t)obj_size[sb] * D_SZ;
#pragma unroll
        for (int i = 0; i < 4; ++i) {
            int k = c4 * 4 + i * 16;
            float4 v = *(const float4*)(srow + k);
            xhS[(D_ID + k + 0) * 64 + sb] = v.x;
            xhS[(D_ID + k + 1) * 64 + sb] = v.y;
            xhS[(D_ID + k + 2) * 64 + sb] = v.z;
            xhS[(D_ID + k + 3) * 64 + sb] = v.w;
        }
        const float* h0row = h0 + (size_t)sb * HH;
#pragma unroll
        for (int i = 0; i < 2; ++i) {
            int k = c4 * 4 + i * 16;   // h0 cols 0..31
            float4 v = *(const float4*)(h0row + k);
            xhS[(DX + k + 0) * 64 + sb] = v.x;
            xhS[(DX + k + 1) * 64 + sb] = v.y;
            xhS[(DX + k + 2) * 64 + sb] = v.z;
            xhS[(DX + k + 3) * 64 + sb] = v.w;
        }
    }
    __syncthreads();
#pragma unroll 16
    for (int k = 0; k < DX; ++k)
        acc += wi[k] * xhS[k * 64 + b];
#pragma unroll 8
    for (int k = 0; k < 32; ++k)
        acc += wh[k] * xhS[(DX + k) * 64 + b];
    __syncthreads();

    // ---- half-stage 2: h0 cols [32,256)
    {
        const float* h0row = h0 + (size_t)sb * HH + 32;
#pragma unroll
        for (int i = 0; i < 14; ++i) {
            int k = c4 * 4 + i * 16;   // 0..223
            float4 v = *(const float4*)(h0row + k);
            xhS[(k + 0) * 64 + sb] = v.x;
            xhS[(k + 1) * 64 + sb] = v.y;
            xhS[(k + 2) * 64 + sb] = v.z;
            xhS[(k + 3) * 64 + sb] = v.w;
        }
    }
    __syncthreads();
#pragma unroll 16
    for (int k = 0; k < 224; ++k)
        acc += wh[32 + k] * xhS[k * 64 + b];

    gS[q * 64 + b] = acc;
    __syncthreads();

    if (tid < 64) {
        float ig = 1.f / (1.f + expf(-gS[tid]));
        float fg = 1.f / (1.f + expf(-gS[64 + tid]));
        float gg = tanhf(gS[128 + tid]);
        float og = 1.f / (1.f + expf(-gS[192 + tid]));
        float c = fg * c0[tid * HH + j] + ig * gg;
        h_new[tid * HH + j] = og * tanhf(c);
    }
}

// =====================================================================
// K2: fused proj + attn.
//   Per block (b, 128-l tile):
//     1. stage Q (HBM gather first, latency hidden under MFMAs below)
//     2. compute hp = hist @ attn_W^T via MFMA with A=attn_W rows (M=d),
//        B=hist rows (N=t); write bf16 C directly into hpS in the exact
//        fragment layout the score MFMA consumes (ds_write_b64 quads).
//        8x redundant per b but only ~0.5 GFLOP total -> removes proj
//        dispatch + boundary + hp global round-trip.
//     3. waves 0/1: sv/rv at t=127 (needs h_new)
//     4. scores MFMA + softmax-over-t + heads (unchanged)
// =====================================================================
__global__ void attn_kernel(const int* __restrict__ cache_lines,
                            const float* __restrict__ obj_id_table,
                            const float* __restrict__ history,
                            const float* __restrict__ h_new,
                            const float* __restrict__ attn_W,
                            const float* __restrict__ pos_table,
                            const float* __restrict__ sv,
                            const float* __restrict__ rv,
                            const float* __restrict__ scorer_W,
                            const float* __restrict__ reuse_W,
                            const float* __restrict__ scorer_b,
                            const float* __restrict__ reuse_b,
                            float* __restrict__ logits,
                            float* __restrict__ out_reuse) {
    int b  = blockIdx.x >> 3;
    int l0 = (blockIdx.x & 7) * 128;
    int tid = threadIdx.x;
    __shared__ unsigned short qS[16384];   // [w][k][lane][8]
    __shared__ unsigned short hpS[16384];  // [k][tt][lane][8]
    __shared__ float s127[2];

    int w = tid >> 6;
    int lane = tid & 63;
    int ln = lane & 31, half = lane >> 5;

    // ---- 1. stage Q (gather issued first)
    {
        int l = tid & 127;
        int cl = cache_lines[b * LL + l0 + l];
        const float* qrow = obj_id_table + (size_t)cl * D_ID;
        int lhi = (l >> 5) * 8, llo = l & 31;
#pragma unroll
        for (int i = 0; i < 8; ++i) {
            int u = 2 * i + (tid >> 7);
            float4 f0 = *(const float4*)(qrow + u * 8);
            float4 f1 = *(const float4*)(qrow + u * 8 + 4);
            *(s16x8*)(qS + (((lhi + (u >> 1)) * 64) + (u & 1) * 32 + llo) * 8) =
                pack8(f0, f1);
        }
    }

    // ---- 2. hp projection: wave w owns d-rows [32w, 32w+32) x all 128 t
    {
        const float* arow = attn_W + (size_t)(32 * w + ln) * HH;
        const float* brow[4];
#pragma unroll
        for (int tt = 0; tt < 4; ++tt) {
            int t = tt * 32 + ln;
            brow[tt] = (t < TT - 1) ? history + ((size_t)b * (TT - 1) + t) * HH
                                    : h_new + (size_t)b * HH;
        }
        f32x16 pacc[4];
#pragma unroll
        for (int tt = 0; tt < 4; ++tt)
#pragma unroll
            for (int rr = 0; rr < 16; ++rr) pacc[tt][rr] = 0.f;

#pragma unroll 4
        for (int ks = 0; ks < 16; ++ks) {
            int off = ks * 16 + half * 8;
            float4 a0 = *(const float4*)(arow + off);
            float4 a1 = *(const float4*)(arow + off + 4);
            s16x8 af = pack8(a0, a1);
#pragma unroll
            for (int tt = 0; tt < 4; ++tt) {
                float4 b0 = *(const float4*)(brow[tt] + off);
                float4 b1 = *(const float4*)(brow[tt] + off + 4);
                pacc[tt] = __builtin_amdgcn_mfma_f32_32x32x16_bf16(
                    af, pack8(b0, b1), pacc[tt], 0, 0, 0);
            }
        }
        // C layout: d = 32w + (r&3)+8*(r>>2)+4*half, t = 32*tt + ln.
        // Consumer frag addr for (t,d): ((d>>4)*4 + t>>5)*512
        //   + ((d>>3)&1)*256 + (t&31)*8 + (d&7)  -> quad r=4qd..4qd+3 is
        //   4 contiguous shorts, 8B-aligned.
#pragma unroll
        for (int tt = 0; tt < 4; ++tt)
#pragma unroll
            for (int qd = 0; qd < 4; ++qd) {
                u16x4 v;
                v[0] = f2bf(pacc[tt][4 * qd + 0]);
                v[1] = f2bf(pacc[tt][4 * qd + 1]);
                v[2] = f2bf(pacc[tt][4 * qd + 2]);
                v[3] = f2bf(pacc[tt][4 * qd + 3]);
                int sa = ((2 * w + (qd >> 1)) * 4 + tt) * 512 +
                         (qd & 1) * 256 + ln * 8 + 4 * half;
                *(u16x4*)(hpS + sa) = v;
            }
    }

    // ---- 3. sv/rv at t=127 (K1 skipped it; needs h_new)
    if (w < 2) {
        const float* wv = w ? reuse_W : scorer_W;
        float a = 0.f;
#pragma unroll
        for (int i = 0; i < 6; ++i) {
            int idx = lane + 64 * i;
            float x = (idx < HH)
                ? h_new[(size_t)b * HH + idx]
                : pos_table[(size_t)(TT - 1) * D_POS + (idx - HH)];
            a += wv[idx] * x;
        }
#pragma unroll
        for (int off = 1; off < 64; off <<= 1) a += __shfl_xor(a, off);
        if (lane == 0) s127[w] = a;
    }
    __syncthreads();

    // ---- 4. scores = Q @ hp^T, softmax over t, heads
    f32x16 acc[4];
#pragma unroll
    for (int tt = 0; tt < 4; ++tt)
#pragma unroll
        for (int rr = 0; rr < 16; ++rr) acc[tt][rr] = 0.f;

    const unsigned short* qw = qS + w * 8 * 512;
#pragma unroll
    for (int k = 0; k < 8; ++k) {
        s16x8 a = *(const s16x8*)(qw + k * 512 + lane * 8);
#pragma unroll
        for (int tt = 0; tt < 4; ++tt) {
            s16x8 bf = *(const s16x8*)(hpS + (k * 4 + tt) * 512 + lane * 8);
            acc[tt] = __builtin_amdgcn_mfma_f32_32x32x16_bf16(a, bf, acc[tt], 0, 0, 0);
        }
    }

    float sv_r[4], rv_r[4];
#pragma unroll
    for (int tt = 0; tt < 4; ++tt) {
        sv_r[tt] = sv[b * TT + tt * 32 + ln];
        rv_r[tt] = rv[b * TT + tt * 32 + ln];
    }
    if (ln == 31) { sv_r[3] = s127[0]; rv_r[3] = s127[1]; }  // t=127 patch
    float sb = scorer_b[0], rb = reuse_b[0];

#pragma unroll
    for (int r = 0; r < 16; ++r) {
        float v0 = acc[0][r], v1 = acc[1][r], v2 = acc[2][r], v3 = acc[3][r];
        float m = fmaxf(fmaxf(v0, v1), fmaxf(v2, v3));
#pragma unroll
        for (int off = 1; off < 32; off <<= 1) m = fmaxf(m, __shfl_xor(m, off));
        float e0 = __expf(v0 - m), e1 = __expf(v1 - m),
              e2 = __expf(v2 - m), e3 = __expf(v3 - m);
        float s  = e0 + e1 + e2 + e3;
        float lg = e0 * sv_r[0] + e1 * sv_r[1] + e2 * sv_r[2] + e3 * sv_r[3];
        float rg = e0 * rv_r[0] + e1 * rv_r[1] + e2 * rv_r[2] + e3 * rv_r[3];
#pragma unroll
        for (int off = 1; off < 32; off <<= 1) {
            s  += __shfl_xor(s, off);
            lg += __shfl_xor(lg, off);
            rg += __shfl_xor(rg, off);
        }
        if (ln == 0) {
            int row = (r & 3) + 8 * (r >> 2) + 4 * half;
            int l = l0 + w * 32 + row;
            logits[b * LL + l] = lg / s + sb;
            out_reuse[b * LL + l] = rg / s + rb;
        }
    }
}

// -------------------------------------- masked softmax over L per batch
__global__ void finalsm_kernel(const float* __restrict__ logits,
                               const int* __restrict__ lengths,
                               float* __restrict__ out_probs) {
    int b = blockIdx.x;
    int tid = threadIdx.x;
    int valid = max(lengths[b], 1);
    float v[4];
    float m = -1e30f;
#pragma unroll
    for (int i = 0; i < 4; ++i) {
        int l = tid + 256 * i;
        v[i] = (l < valid) ? logits[b * LL + l] : -1e30f;
        m = fmaxf(m, v[i]);
    }
#pragma unroll
    for (int off = 1; off < 64; off <<= 1) m = fmaxf(m, __shfl_xor(m, off));
    __shared__ float redm[4];
    __shared__ float reds[4];
    int wave = tid >> 6;
    if ((tid & 63) == 0) redm[wave] = m;
    __syncthreads();
    m = fmaxf(fmaxf(redm[0], redm[1]), fmaxf(redm[2], redm[3]));
    float e[4];
    float s = 0.f;
#pragma unroll
    for (int i = 0; i < 4; ++i) {
        int l = tid + 256 * i;
        e[i] = (l < valid) ? expf(v[i] - m) : 0.f;
        s += e[i];
    }
#pragma unroll
    for (int off = 1; off < 64; off <<= 1) s += __shfl_xor(s, off);
    if ((tid & 63) == 0) reds[wave] = s;
    __syncthreads();
    s = reds[0] + reds[1] + reds[2] + reds[3];
    float inv = 1.f / s;
#pragma unroll
    for (int i = 0; i < 4; ++i)
        out_probs[b * LL + tid + 256 * i] = e[i] * inv;
}

extern "C" void kernel_launch(void* const* d_in, const int* in_sizes, int n_in,
                              void* d_out, int out_size, void* d_ws, size_t ws_size,
                              hipStream_t stream) {
    const int*   obj_id         = (const int*)d_in[0];
    const int*   obj_size       = (const int*)d_in[1];
    const int*   cache_lines    = (const int*)d_in[2];
    const int*   lengths        = (const int*)d_in[3];
    const float* c0             = (const float*)d_in[4];
    const float* h0             = (const float*)d_in[5];
    const float* history        = (const float*)d_in[6];
    const float* obj_id_table   = (const float*)d_in[7];
    const float* obj_size_table = (const float*)d_in[8];
    const float* pos_table      = (const float*)d_in[9];
    const float* W_ih           = (const float*)d_in[10];
    const float* W_hh           = (const float*)d_in[11];
    const float* b_ih           = (const float*)d_in[12];
    const float* b_hh           = (const float*)d_in[13];
    const float* attn_W         = (const float*)d_in[14];
    const float* scorer_W       = (const float*)d_in[15];
    const float* scorer_b       = (const float*)d_in[16];
    const float* reuse_W        = (const float*)d_in[17];
    const float* reuse_b        = (const float*)d_in[18];

    float* out = (float*)d_out;
    float* out_probs = out;                 // (B, L)
    float* out_reuse = out + BB * LL;       // (B, L)

    char* ws = (char*)d_ws;
    float* h_new  = (float*)(ws);            // 64 KB
    float* sv     = (float*)(ws + 65536);    // 32 KB
    float* rv     = (float*)(ws + 98304);    // 32 KB
    float* logits = (float*)(ws + 131072);   // 256 KB

    // 3 dispatches (was 5): each removed boundary kills a launch +
    // cross-XCD L2 coherency drain (cf. R5: device-scope fences ~70us).
    hipLaunchKernelGGL(gates_kernel, dim3(HH + BB), dim3(256), 0, stream,
                       obj_id, obj_size, h0, c0, obj_id_table, obj_size_table,
                       history, pos_table, W_ih, W_hh, b_ih, b_hh,
                       scorer_W, reuse_W, h_new, sv, rv);
    hipLaunchKernelGGL(attn_kernel, dim3(BB * 8), dim3(256), 0, stream,
                       cache_lines, obj_id_table, history, h_new, attn_W,
                       pos_table, sv, rv, scorer_W, reuse_W,
                       scorer_b, reuse_b, logits, out_reuse);
    hipLaunchKernelGGL(finalsm_kernel, dim3(BB), dim3(256), 0, stream,
                       logits, lengths, out_probs);
}